// Round 1
// baseline (339.152 us; speedup 1.0000x reference)
//
#include <hip/hip_runtime.h>
#include <stdint.h>

typedef __attribute__((ext_vector_type(8))) short short8;
typedef __attribute__((ext_vector_type(4))) float f32x4;
typedef __attribute__((ext_vector_type(4))) unsigned short us4;

#define B_ 4
#define N_ 2048
#define C_ 1024
#define H_ 16
#define D_ 64

__device__ __forceinline__ unsigned short f2bf(float f) {
  union { float f; unsigned u; } v; v.f = f;
  unsigned u = v.u;
  u += 0x7fffu + ((u >> 16) & 1u);
  return (unsigned short)(u >> 16);
}

__device__ __forceinline__ void glds16(const unsigned short* g, const unsigned short* l) {
  __builtin_amdgcn_global_load_lds(
      (const __attribute__((address_space(1))) void*)(uintptr_t)g,
      (__attribute__((address_space(3))) void*)(uintptr_t)l, 16, 0, 0);
}

__device__ __forceinline__ f32x4 mfma16(short8 a, short8 b, f32x4 c) {
  return __builtin_amdgcn_mfma_f32_16x16x32_bf16(a, b, c, 0, 0, 0);
}

// ---------------- prep: row std (ddof=1) -> xn bf16, x bf16 ----------------
__global__ __launch_bounds__(256) void prep_k(const float* __restrict__ x,
                                              const float* __restrict__ gamma,
                                              unsigned short* __restrict__ xn,
                                              unsigned short* __restrict__ xb) {
  const int row = blockIdx.x, t = threadIdx.x;
  const float4 v = ((const float4*)(x + (size_t)row * C_))[t];
  float s1 = v.x + v.y + v.z + v.w;
  float s2 = v.x * v.x + v.y * v.y + v.z * v.z + v.w * v.w;
#pragma unroll
  for (int off = 32; off > 0; off >>= 1) {
    s1 += __shfl_down(s1, off);
    s2 += __shfl_down(s2, off);
  }
  __shared__ float r1[4], r2[4];
  if ((t & 63) == 0) { r1[t >> 6] = s1; r2[t >> 6] = s2; }
  __syncthreads();
  s1 = r1[0] + r1[1] + r1[2] + r1[3];
  s2 = r2[0] + r2[1] + r2[2] + r2[3];
  // ref: std = sqrt((sumsq - sum^2/C)/(C-1)); NO mean subtraction in xn.
  const float var = (s2 - s1 * s1 * (1.0f / C_)) * (1.0f / (C_ - 1));
  const float rstd = 1.0f / (sqrtf(var) + 1e-7f);
  const float4 gv = ((const float4*)gamma)[t];
  us4 a, b;
  a.x = f2bf(v.x); a.y = f2bf(v.y); a.z = f2bf(v.z); a.w = f2bf(v.w);
  b.x = f2bf(v.x * rstd * gv.x); b.y = f2bf(v.y * rstd * gv.y);
  b.z = f2bf(v.z * rstd * gv.z); b.w = f2bf(v.w * rstd * gv.w);
  ((us4*)(xb + (size_t)row * C_))[t] = a;
  ((us4*)(xn + (size_t)row * C_))[t] = b;
}

// ---------------- fp32 -> bf16 cast ----------------
__global__ __launch_bounds__(256) void cast_k(const float* __restrict__ s,
                                              unsigned short* __restrict__ d, int n4) {
  const int i = blockIdx.x * 256 + threadIdx.x;
  if (i >= n4) return;
  const float4 v = ((const float4*)s)[i];
  us4 o; o.x = f2bf(v.x); o.y = f2bf(v.y); o.z = f2bf(v.z); o.w = f2bf(v.w);
  ((us4*)d)[i] = o;
}

// ---------------- GEMM: C[M,N] = A[M,K] * Bw[N,K]^T (both K-major) ----------
// m97 structure: 128x128 tile, BK=32, 4 waves each 64x64, global_load_lds(16B),
// XOR swizzle blk^=(row>>1)&3 on the 64B-stride LDS rows (breaks 8-way conflict).
// EPI 0: bf16 out, *uscale.  EPI 1: fp32 out, *colscale[col].
template <int EPI>
__global__ __launch_bounds__(256, 2) void gemm_bt(const unsigned short* __restrict__ A,
                                                  const unsigned short* __restrict__ Bw,
                                                  void* __restrict__ Cout,
                                                  const float* __restrict__ colscale,
                                                  float uscale, int M, int N, int K) {
  __shared__ unsigned short At[128 * 32];
  __shared__ unsigned short Bt[128 * 32];
  const int t = threadIdx.x;
  const int w = t >> 6, l = t & 63;
  const int ql = l & 15, g = l >> 4;
  const int wr = (w >> 1) * 64, wc = (w & 1) * 64;
  const int m0 = blockIdx.y * 128, n0 = blockIdx.x * 128;

  const int pr0 = t >> 2, pb0 = t & 3;
  const int lb0 = pb0 ^ ((pr0 >> 1) & 3);
  const int pr1 = 64 + (t >> 2);
  const int lb1 = pb0 ^ ((pr1 >> 1) & 3);
  const unsigned short* Ab = A + (size_t)m0 * K;
  const unsigned short* Bb = Bw + (size_t)n0 * K;

  f32x4 acc[4][4];
#pragma unroll
  for (int i = 0; i < 4; ++i)
#pragma unroll
    for (int j = 0; j < 4; ++j) acc[i][j] = f32x4{0.f, 0.f, 0.f, 0.f};

  for (int k0 = 0; k0 < K; k0 += 32) {
    glds16(Ab + (size_t)pr0 * K + k0 + lb0 * 8, &At[w * 512]);
    glds16(Ab + (size_t)pr1 * K + k0 + lb1 * 8, &At[2048 + w * 512]);
    glds16(Bb + (size_t)pr0 * K + k0 + lb0 * 8, &Bt[w * 512]);
    glds16(Bb + (size_t)pr1 * K + k0 + lb1 * 8, &Bt[2048 + w * 512]);
    __syncthreads();  // drains vmcnt -> staged data visible
    short8 af[4], bfr[4];
#pragma unroll
    for (int i = 0; i < 4; ++i) {
      const int row = wr + i * 16 + ql;
      af[i] = *(const short8*)&At[row * 32 + ((g ^ ((row >> 1) & 3)) * 8)];
    }
#pragma unroll
    for (int i = 0; i < 4; ++i) {
      const int row = wc + i * 16 + ql;
      bfr[i] = *(const short8*)&Bt[row * 32 + ((g ^ ((row >> 1) & 3)) * 8)];
    }
#pragma unroll
    for (int mi = 0; mi < 4; ++mi)
#pragma unroll
      for (int ni = 0; ni < 4; ++ni)
        acc[mi][ni] = mfma16(af[mi], bfr[ni], acc[mi][ni]);
    __syncthreads();  // all waves done reading before next stage
  }

  if (EPI == 0) {
    unsigned short* C = (unsigned short*)Cout;
#pragma unroll
    for (int mi = 0; mi < 4; ++mi)
#pragma unroll
      for (int ni = 0; ni < 4; ++ni) {
        const int col = n0 + wc + ni * 16 + ql;
#pragma unroll
        for (int r = 0; r < 4; ++r) {
          const int row = m0 + wr + mi * 16 + g * 4 + r;
          C[(size_t)row * N + col] = f2bf(acc[mi][ni][r] * uscale);
        }
      }
  } else {
    float* C = (float*)Cout;
#pragma unroll
    for (int mi = 0; mi < 4; ++mi)
#pragma unroll
      for (int ni = 0; ni < 4; ++ni) {
        const int col = n0 + wc + ni * 16 + ql;
        const float cs = colscale[col];
#pragma unroll
        for (int r = 0; r < 4; ++r) {
          const int row = m0 + wr + mi * 16 + g * 4 + r;
          C[(size_t)row * N + col] = acc[mi][ni][r] * cs;
        }
      }
  }
}

// ---------------- flash attention (MQA: K/V shared across heads) ------------
// block = (b, h, 64 q-rows); 4 waves x 16 q-rows. Swapped QK^T: S^T = K*Q so
// per-q softmax reduction is shfl_xor(16/32). P bounced through LDS as the
// PV B-operand; V staged transposed [d][kv]. K LDS XOR-swizzled (128B rows).
__global__ __launch_bounds__(256) void attn_k(const unsigned short* __restrict__ qb,
                                              const unsigned short* __restrict__ kvb,
                                              unsigned short* __restrict__ ao) {
  __shared__ unsigned short Kt[32 * 64];      // [kv][d], blk^= (kv&7) swizzle
  __shared__ unsigned short Vt[64 * 40];      // [d][kv] padded stride 40
  __shared__ unsigned short Pl[4][16 * 40];   // per-wave [q][kv] stride 40

  const int idx = blockIdx.x;
  const int qc = idx & 31, h = (idx >> 5) & 15, b = idx >> 9;
  const int t = threadIdx.x, w = t >> 6;
  const int ql = (t & 63) & 15, g = (t & 63) >> 4;
  const int q0 = qc * 64 + w * 16;

  const unsigned short* qrow = qb + (size_t)(b * N_ + q0 + ql) * C_ + h * D_;
  const short8 Qf0 = *(const short8*)(qrow + g * 8);
  const short8 Qf1 = *(const short8*)(qrow + 32 + g * 8);

  const int prow = t >> 3;
  const int kcol = (((t & 7) ^ (prow & 7))) * 8;  // logical col of this thread's 16B
  const unsigned short* kvbase = kvb + (size_t)(b * N_) * 128;

  f32x4 o[4];
#pragma unroll
  for (int i = 0; i < 4; ++i) o[i] = f32x4{0.f, 0.f, 0.f, 0.f};
  float mrun = -1e30f, lrun = 0.f;
  const int sw = ql & 7;

  for (int kt = 0; kt < 64; ++kt) {
    __syncthreads();  // previous tile's LDS reads complete
    const unsigned short* src = kvbase + (size_t)(kt * 32 + prow) * 128 + kcol;
    glds16(src, &Kt[w * 512]);
    const short8 vv = *(const short8*)(src + 64);
#pragma unroll
    for (int j = 0; j < 8; ++j)
      Vt[(kcol + j) * 40 + prow] = (unsigned short)vv[j];
    __syncthreads();  // staging visible

    const short8 kA0 = *(const short8*)&Kt[ql * 64 + ((g ^ sw) * 8)];
    const short8 kA1 = *(const short8*)&Kt[ql * 64 + (((g + 4) ^ sw) * 8)];
    const short8 kB0 = *(const short8*)&Kt[(16 + ql) * 64 + ((g ^ sw) * 8)];
    const short8 kB1 = *(const short8*)&Kt[(16 + ql) * 64 + (((g + 4) ^ sw) * 8)];
    const f32x4 z = {0.f, 0.f, 0.f, 0.f};
    f32x4 sA = mfma16(kA0, Qf0, z);
    sA = mfma16(kA1, Qf1, sA);
    f32x4 sB = mfma16(kB0, Qf0, z);
    sB = mfma16(kB1, Qf1, sB);

    // online softmax: lane holds kv = {4g..4g+3, 16+4g..16+4g+3} for q = ql
    float tmax = fmaxf(fmaxf(fmaxf(sA[0], sA[1]), fmaxf(sA[2], sA[3])),
                       fmaxf(fmaxf(sB[0], sB[1]), fmaxf(sB[2], sB[3])));
    tmax = fmaxf(tmax, __shfl_xor(tmax, 16));
    tmax = fmaxf(tmax, __shfl_xor(tmax, 32));
    const float mn = fmaxf(mrun, tmax);
    const float corr = __expf(mrun - mn);
    float pA[4], pB[4], ps = 0.f;
#pragma unroll
    for (int r = 0; r < 4; ++r) { pA[r] = __expf(sA[r] - mn); ps += pA[r]; }
#pragma unroll
    for (int r = 0; r < 4; ++r) { pB[r] = __expf(sB[r] - mn); ps += pB[r]; }
    ps += __shfl_xor(ps, 16);
    ps += __shfl_xor(ps, 32);
    lrun = lrun * corr + ps;
    mrun = mn;
#pragma unroll
    for (int i = 0; i < 4; ++i) o[i] *= corr;

    unsigned short* pw = &Pl[w][ql * 40];
#pragma unroll
    for (int r = 0; r < 4; ++r) {
      pw[g * 4 + r] = f2bf(pA[r]);
      pw[16 + g * 4 + r] = f2bf(pB[r]);
    }
    __syncthreads();  // P visible (cross-lane within wave)
    const short8 pf = *(const short8*)&Pl[w][ql * 40 + g * 8];
#pragma unroll
    for (int dt = 0; dt < 4; ++dt) {
      const short8 vf = *(const short8*)&Vt[(dt * 16 + ql) * 40 + g * 8];
      o[dt] = mfma16(vf, pf, o[dt]);  // o^T[d][q]
    }
  }

  const float inv = 1.0f / lrun;
  unsigned short* orow = ao + (size_t)(b * N_ + q0 + ql) * C_ + h * D_;
#pragma unroll
  for (int dt = 0; dt < 4; ++dt) {
    us4 st;
    st.x = f2bf(o[dt][0] * inv);
    st.y = f2bf(o[dt][1] * inv);
    st.z = f2bf(o[dt][2] * inv);
    st.w = f2bf(o[dt][3] * inv);
    *(us4*)(orow + dt * 16 + g * 4) = st;
  }
}

extern "C" void kernel_launch(void* const* d_in, const int* in_sizes, int n_in,
                              void* d_out, int out_size, void* d_ws, size_t ws_size,
                              hipStream_t stream) {
  const float* x = (const float*)d_in[0];
  const float* gamma = (const float*)d_in[1];
  const float* Wq = (const float*)d_in[2];
  const float* Wkv = (const float*)d_in[3];
  const float* Wo = (const float*)d_in[4];
  const float* ls = (const float*)d_in[5];
  float* out = (float*)d_out;

  unsigned short* ws = (unsigned short*)d_ws;
  const size_t R = (size_t)B_ * N_;  // 8192 rows
  unsigned short* xn = ws;                       // R*C
  unsigned short* xb = xn + R * C_;              // R*C
  unsigned short* qbuf = xb + R * C_;            // R*C
  unsigned short* kvb = qbuf + R * C_;           // R*128
  unsigned short* aob = kvb + R * 128;           // R*C
  unsigned short* wqb = aob + R * C_;            // C*C
  unsigned short* wkvb = wqb + (size_t)C_ * C_;  // 128*C
  unsigned short* wob = wkvb + (size_t)128 * C_; // C*C   (total ~70 MB)

  prep_k<<<(int)R, 256, 0, stream>>>(x, gamma, xn, xb);
  cast_k<<<(C_ * C_ / 4) / 256, 256, 0, stream>>>(Wq, wqb, C_ * C_ / 4);
  cast_k<<<(128 * C_ / 4) / 256, 256, 0, stream>>>(Wkv, wkvb, 128 * C_ / 4);
  cast_k<<<(C_ * C_ / 4) / 256, 256, 0, stream>>>(Wo, wob, C_ * C_ / 4);

  // q = xn @ Wq^T, scale folded (1/sqrt(64) = 0.125)
  gemm_bt<0><<<dim3(C_ / 128, R / 128), 256, 0, stream>>>(xn, wqb, qbuf, nullptr,
                                                          0.125f, (int)R, C_, C_);
  // kv = x @ Wkv^T (RAW x per reference)
  gemm_bt<0><<<dim3(1, R / 128), 256, 0, stream>>>(xb, wkvb, kvb, nullptr, 1.0f,
                                                   (int)R, 128, C_);
  attn_k<<<B_ * H_ * (N_ / 64), 256, 0, stream>>>(qbuf, kvb, aob);
  // out = (ao @ Wo^T) * ls_scale[col], fp32
  gemm_bt<1><<<dim3(C_ / 128, R / 128), 256, 0, stream>>>(aob, wob, out, ls, 1.0f,
                                                          (int)R, C_, C_);
}

// Round 5
// 217.802 us; speedup vs baseline: 1.5572x; 1.5572x over previous
//
#include <hip/hip_runtime.h>
#include <stdint.h>

typedef __attribute__((ext_vector_type(8))) short short8;
typedef __attribute__((ext_vector_type(4))) float f32x4;
typedef __attribute__((ext_vector_type(4))) unsigned short us4;

#define B_ 4
#define N_ 2048
#define C_ 1024
#define H_ 16
#define D_ 64
#define PSTR 68  // P-row stride: 64 kv cols + 4 pad (round-2..4 bug: was 40)

__device__ __forceinline__ unsigned short f2bf(float f) {
  union { float f; unsigned u; } v; v.f = f;
  unsigned u = v.u;
  u += 0x7fffu + ((u >> 16) & 1u);
  return (unsigned short)(u >> 16);
}

__device__ __forceinline__ void glds16(const unsigned short* g, const unsigned short* l) {
  __builtin_amdgcn_global_load_lds(
      (const __attribute__((address_space(1))) void*)(uintptr_t)g,
      (__attribute__((address_space(3))) void*)(uintptr_t)l, 16, 0, 0);
}

__device__ __forceinline__ f32x4 mfma16(short8 a, short8 b, f32x4 c) {
  return __builtin_amdgcn_mfma_f32_16x16x32_bf16(a, b, c, 0, 0, 0);
}

// ---------------- prep: row std (ddof=1) -> xn bf16, x bf16 ----------------
__global__ __launch_bounds__(256) void prep_k(const float* __restrict__ x,
                                              const float* __restrict__ gamma,
                                              unsigned short* __restrict__ xn,
                                              unsigned short* __restrict__ xb) {
  const int row = blockIdx.x, t = threadIdx.x;
  const float4 v = ((const float4*)(x + (size_t)row * C_))[t];
  float s1 = v.x + v.y + v.z + v.w;
  float s2 = v.x * v.x + v.y * v.y + v.z * v.z + v.w * v.w;
#pragma unroll
  for (int off = 32; off > 0; off >>= 1) {
    s1 += __shfl_down(s1, off);
    s2 += __shfl_down(s2, off);
  }
  __shared__ float r1[4], r2[4];
  if ((t & 63) == 0) { r1[t >> 6] = s1; r2[t >> 6] = s2; }
  __syncthreads();
  s1 = r1[0] + r1[1] + r1[2] + r1[3];
  s2 = r2[0] + r2[1] + r2[2] + r2[3];
  const float var = (s2 - s1 * s1 * (1.0f / C_)) * (1.0f / (C_ - 1));
  const float rstd = 1.0f / (sqrtf(var) + 1e-7f);
  const float4 gv = ((const float4*)gamma)[t];
  us4 a, b;
  a.x = f2bf(v.x); a.y = f2bf(v.y); a.z = f2bf(v.z); a.w = f2bf(v.w);
  b.x = f2bf(v.x * rstd * gv.x); b.y = f2bf(v.y * rstd * gv.y);
  b.z = f2bf(v.z * rstd * gv.z); b.w = f2bf(v.w * rstd * gv.w);
  ((us4*)(xb + (size_t)row * C_))[t] = a;
  ((us4*)(xn + (size_t)row * C_))[t] = b;
}

// ---------------- fp32 -> bf16 cast ----------------
__global__ __launch_bounds__(256) void cast_k(const float* __restrict__ s,
                                              unsigned short* __restrict__ d, int n4) {
  const int i = blockIdx.x * 256 + threadIdx.x;
  if (i >= n4) return;
  const float4 v = ((const float4*)s)[i];
  us4 o; o.x = f2bf(v.x); o.y = f2bf(v.y); o.z = f2bf(v.z); o.w = f2bf(v.w);
  ((us4*)d)[i] = o;
}

// ---------------- V transpose: kvb[n][64+d] -> vtb[b][d][n%2048] ------------
__global__ __launch_bounds__(256) void vtrans_k(const unsigned short* __restrict__ kvb,
                                                unsigned short* __restrict__ vtb) {
  __shared__ unsigned short T[64][68];
  const int t = threadIdx.x, nt = blockIdx.x;
  const int r = t >> 2, c4 = t & 3;
  const unsigned short* src = kvb + (size_t)(nt * 64 + r) * 128 + 64 + c4 * 16;
  *(short8*)&T[r][c4 * 16] = *(const short8*)src;
  *(short8*)&T[r][c4 * 16 + 8] = *(const short8*)(src + 8);
  __syncthreads();
  const int d = t >> 2, nq = t & 3;
  const int b = nt >> 5, nn0 = (nt & 31) * 64 + nq * 16;
  unsigned short* dst = vtb + ((size_t)b * 64 + d) * 2048 + nn0;
  short8 o0, o1;
#pragma unroll
  for (int j = 0; j < 8; ++j) {
    o0[j] = (short)T[nq * 16 + j][d];
    o1[j] = (short)T[nq * 16 + 8 + j][d];
  }
  *(short8*)dst = o0;
  *(short8*)(dst + 8) = o1;
}

// ---------------- GEMM: C[M,N] = A[M,K] * Bw[N,K]^T ------------------------
template <int EPI>
__global__ __launch_bounds__(256, 2) void gemm_bt(const unsigned short* __restrict__ A,
                                                  const unsigned short* __restrict__ Bw,
                                                  void* __restrict__ Cout,
                                                  const float* __restrict__ colscale,
                                                  float uscale, int M, int N, int K) {
  __shared__ unsigned short At[128 * 32];
  __shared__ unsigned short Bt[128 * 32];
  const int t = threadIdx.x;
  const int w = t >> 6, l = t & 63;
  const int ql = l & 15, g = l >> 4;
  const int wr = (w >> 1) * 64, wc = (w & 1) * 64;
  const int m0 = blockIdx.y * 128, n0 = blockIdx.x * 128;

  const int pr0 = t >> 2, pb0 = t & 3;
  const int lb0 = pb0 ^ ((pr0 >> 1) & 3);
  const int pr1 = 64 + (t >> 2);
  const int lb1 = pb0 ^ ((pr1 >> 1) & 3);
  const unsigned short* Ab = A + (size_t)m0 * K;
  const unsigned short* Bb = Bw + (size_t)n0 * K;

  f32x4 acc[4][4];
#pragma unroll
  for (int i = 0; i < 4; ++i)
#pragma unroll
    for (int j = 0; j < 4; ++j) acc[i][j] = f32x4{0.f, 0.f, 0.f, 0.f};

  for (int k0 = 0; k0 < K; k0 += 32) {
    glds16(Ab + (size_t)pr0 * K + k0 + lb0 * 8, &At[w * 512]);
    glds16(Ab + (size_t)pr1 * K + k0 + lb1 * 8, &At[2048 + w * 512]);
    glds16(Bb + (size_t)pr0 * K + k0 + lb0 * 8, &Bt[w * 512]);
    glds16(Bb + (size_t)pr1 * K + k0 + lb1 * 8, &Bt[2048 + w * 512]);
    __syncthreads();
    short8 af[4], bfr[4];
#pragma unroll
    for (int i = 0; i < 4; ++i) {
      const int row = wr + i * 16 + ql;
      af[i] = *(const short8*)&At[row * 32 + ((g ^ ((row >> 1) & 3)) * 8)];
    }
#pragma unroll
    for (int i = 0; i < 4; ++i) {
      const int row = wc + i * 16 + ql;
      bfr[i] = *(const short8*)&Bt[row * 32 + ((g ^ ((row >> 1) & 3)) * 8)];
    }
#pragma unroll
    for (int mi = 0; mi < 4; ++mi)
#pragma unroll
      for (int ni = 0; ni < 4; ++ni)
        acc[mi][ni] = mfma16(af[mi], bfr[ni], acc[mi][ni]);
    __syncthreads();
  }

  if (EPI == 0) {
    unsigned short* C = (unsigned short*)Cout;
#pragma unroll
    for (int mi = 0; mi < 4; ++mi)
#pragma unroll
      for (int ni = 0; ni < 4; ++ni) {
        const int col = n0 + wc + ni * 16 + ql;
#pragma unroll
        for (int r = 0; r < 4; ++r) {
          const int row = m0 + wr + mi * 16 + g * 4 + r;
          C[(size_t)row * N + col] = f2bf(acc[mi][ni][r] * uscale);
        }
      }
  } else {
    float* C = (float*)Cout;
#pragma unroll
    for (int mi = 0; mi < 4; ++mi)
#pragma unroll
      for (int ni = 0; ni < 4; ++ni) {
        const int col = n0 + wc + ni * 16 + ql;
        const float cs = colscale[col];
#pragma unroll
        for (int r = 0; r < 4; ++r) {
          const int row = m0 + wr + mi * 16 + g * 4 + r;
          C[(size_t)row * N + col] = acc[mi][ni][r] * cs;
        }
      }
  }
}

// ---------------- flash attention (MQA) -------------------------------------
// block = (b, hd, 128 q); 4 waves x 32 q (2 q-subtiles). KVBLK=64, 32 tiles.
// K LDS [64 kv][64 d], V^T LDS [64 d][64 kv]; both staged by glds16 with the
// verified XOR swizzle (LDS[r][blk] = global[r][blk ^ (r&7)], achieved by
// pre-swizzling the per-lane GLOBAL source — rule #21), read back with the
// matching swizzled ds_read_b128. Softmax in exp2 domain (log2e folded into
// the Q-GEMM scale), defer-max THR=8. P exchange barrier-protected, stride
// PSTR=68 (>=64 kv cols — the rounds-2..4 overflow bug).
__global__ __launch_bounds__(256, 3) void attn_k(const unsigned short* __restrict__ qb,
                                                 const unsigned short* __restrict__ kvb,
                                                 const unsigned short* __restrict__ vtb,
                                                 unsigned short* __restrict__ ao) {
  __shared__ unsigned short Kt[64 * 64];
  __shared__ unsigned short Vt[64 * 64];
  __shared__ unsigned short Pl[4][32 * PSTR];

  const int idx = blockIdx.x;
  const int qc = idx & 15, hd = (idx >> 4) & 15, b = idx >> 8;
  const int t = threadIdx.x, w = t >> 6, l = t & 63;
  const int ql = l & 15, g = l >> 4;
  const int q0 = qc * 128 + w * 32;

  // Q fragments (scale incl. log2e folded into the Q GEMM epilogue)
  const unsigned short* qbase = qb + (size_t)(b * N_ + q0) * C_ + hd * D_;
  short8 Qf[2][2];
#pragma unroll
  for (int qs = 0; qs < 2; ++qs)
#pragma unroll
    for (int h = 0; h < 2; ++h)
      Qf[qs][h] = *(const short8*)(qbase + (size_t)(16 * qs + ql) * C_ + 32 * h + 8 * g);

  const unsigned short* kvrow = kvb + (size_t)(b * N_) * 128;
  const unsigned short* vtrow = vtb + (size_t)b * 64 * 2048;
  const int sr = l >> 3;                 // sub-row within an 8-row stage slab
  const int blk = ((l & 7) ^ sr) << 3;   // pre-swizzled source block (shorts)
  const int row0 = 16 * w + sr;          // rows covered by this wave's 2 issues
  const int row1 = row0 + 8;

  f32x4 o[2][4];
#pragma unroll
  for (int qs = 0; qs < 2; ++qs)
#pragma unroll
    for (int dt = 0; dt < 4; ++dt) o[qs][dt] = f32x4{0.f, 0.f, 0.f, 0.f};
  float m[2] = {-1e30f, -1e30f}, lsum[2] = {0.f, 0.f};

  for (int kt = 0; kt < 32; ++kt) {
    __syncthreads();  // previous tile's LDS reads complete
    glds16(kvrow + (size_t)(kt * 64 + row0) * 128 + blk, &Kt[(2 * w) * 512]);
    glds16(kvrow + (size_t)(kt * 64 + row1) * 128 + blk, &Kt[(2 * w + 1) * 512]);
    glds16(vtrow + (size_t)row0 * 2048 + kt * 64 + blk, &Vt[(2 * w) * 512]);
    glds16(vtrow + (size_t)row1 * 2048 + kt * 64 + blk, &Vt[(2 * w + 1) * 512]);
    __syncthreads();  // staging visible (vmcnt drained by barrier)

    const int sw = ql & 7;
    short8 Kf[4][2];
#pragma unroll
    for (int c = 0; c < 4; ++c) {
      const int roff = (16 * c + ql) * 64;
      Kf[c][0] = *(const short8*)&Kt[roff + ((g ^ sw) << 3)];
      Kf[c][1] = *(const short8*)&Kt[roff + (((g + 4) ^ sw) << 3)];
    }

#pragma unroll
    for (int qs = 0; qs < 2; ++qs) {
      f32x4 s[4];
#pragma unroll
      for (int c = 0; c < 4; ++c) {
        f32x4 acc = {0.f, 0.f, 0.f, 0.f};
        acc = mfma16(Kf[c][0], Qf[qs][0], acc);
        acc = mfma16(Kf[c][1], Qf[qs][1], acc);
        s[c] = acc;
      }
      float tm = fmaxf(fmaxf(s[0][0], s[0][1]), fmaxf(s[0][2], s[0][3]));
#pragma unroll
      for (int c = 1; c < 4; ++c)
        tm = fmaxf(tm, fmaxf(fmaxf(s[c][0], s[c][1]), fmaxf(s[c][2], s[c][3])));
      tm = fmaxf(tm, __shfl_xor(tm, 16));
      tm = fmaxf(tm, __shfl_xor(tm, 32));
      if (!__all(tm <= m[qs] + 8.0f)) {  // defer-max (T13)
        const float mn = fmaxf(m[qs], tm);
        const float corr = __builtin_amdgcn_exp2f(m[qs] - mn);
        lsum[qs] *= corr;
#pragma unroll
        for (int dt = 0; dt < 4; ++dt) o[qs][dt] *= corr;
        m[qs] = mn;
      }
      float ps = 0.f;
#pragma unroll
      for (int c = 0; c < 4; ++c) {
        const float p0 = __builtin_amdgcn_exp2f(s[c][0] - m[qs]);
        const float p1 = __builtin_amdgcn_exp2f(s[c][1] - m[qs]);
        const float p2 = __builtin_amdgcn_exp2f(s[c][2] - m[qs]);
        const float p3 = __builtin_amdgcn_exp2f(s[c][3] - m[qs]);
        ps += (p0 + p1) + (p2 + p3);
        us4 pq;
        pq.x = f2bf(p0); pq.y = f2bf(p1); pq.z = f2bf(p2); pq.w = f2bf(p3);
        *(us4*)&Pl[w][(16 * qs + ql) * PSTR + 16 * c + 4 * g] = pq;
      }
      ps += __shfl_xor(ps, 16);
      ps += __shfl_xor(ps, 32);
      lsum[qs] += ps;
    }

    __syncthreads();  // P visible (barrier-protected exchange)

    // V^T fragments (after softmax to cap live registers)
    short8 Vf[4][2];
#pragma unroll
    for (int dt = 0; dt < 4; ++dt) {
      const int roff = (16 * dt + ql) * 64;
      Vf[dt][0] = *(const short8*)&Vt[roff + ((g ^ sw) << 3)];
      Vf[dt][1] = *(const short8*)&Vt[roff + (((g + 4) ^ sw) << 3)];
    }
    short8 Pf[2][2];
#pragma unroll
    for (int qs = 0; qs < 2; ++qs)
#pragma unroll
      for (int h = 0; h < 2; ++h)
        Pf[qs][h] = *(const short8*)&Pl[w][(16 * qs + ql) * PSTR + 32 * h + 8 * g];

#pragma unroll
    for (int qs = 0; qs < 2; ++qs)
#pragma unroll
      for (int dt = 0; dt < 4; ++dt) {
        f32x4 acc = o[qs][dt];
        acc = mfma16(Vf[dt][0], Pf[qs][0], acc);
        acc = mfma16(Vf[dt][1], Pf[qs][1], acc);
        o[qs][dt] = acc;  // o^T[d][q]
      }
  }

#pragma unroll
  for (int qs = 0; qs < 2; ++qs) {
    const float inv = 1.0f / lsum[qs];
    unsigned short* orow = ao + (size_t)(b * N_ + q0 + 16 * qs + ql) * C_ + hd * D_;
#pragma unroll
    for (int dt = 0; dt < 4; ++dt) {
      us4 st;
      st.x = f2bf(o[qs][dt][0] * inv);
      st.y = f2bf(o[qs][dt][1] * inv);
      st.z = f2bf(o[qs][dt][2] * inv);
      st.w = f2bf(o[qs][dt][3] * inv);
      *(us4*)(orow + dt * 16 + 4 * g) = st;
    }
  }
}

extern "C" void kernel_launch(void* const* d_in, const int* in_sizes, int n_in,
                              void* d_out, int out_size, void* d_ws, size_t ws_size,
                              hipStream_t stream) {
  const float* x = (const float*)d_in[0];
  const float* gamma = (const float*)d_in[1];
  const float* Wq = (const float*)d_in[2];
  const float* Wkv = (const float*)d_in[3];
  const float* Wo = (const float*)d_in[4];
  const float* ls = (const float*)d_in[5];
  float* out = (float*)d_out;

  unsigned short* ws = (unsigned short*)d_ws;
  const size_t R = (size_t)B_ * N_;  // 8192 rows
  unsigned short* xn = ws;                       // R*C
  unsigned short* xb = xn + R * C_;              // R*C
  unsigned short* qbuf = xb + R * C_;            // R*C
  unsigned short* kvb = qbuf + R * C_;           // R*128
  unsigned short* aob = kvb + R * 128;           // R*C
  unsigned short* wqb = aob + R * C_;            // C*C
  unsigned short* wkvb = wqb + (size_t)C_ * C_;  // 128*C
  unsigned short* wob = wkvb + (size_t)128 * C_; // C*C  (= round-1 footprint)
  // vtb ALIASES wqb: Wq-bf16 is dead after the Q-GEMM; vtrans fully rewrites
  // this region every call before attn reads it (graph-replay deterministic).
  unsigned short* vtb = wqb;                     // 4*64*2048 <= C*C

  prep_k<<<(int)R, 256, 0, stream>>>(x, gamma, xn, xb);
  cast_k<<<(C_ * C_ / 4) / 256, 256, 0, stream>>>(Wq, wqb, C_ * C_ / 4);
  cast_k<<<(128 * C_ / 4) / 256, 256, 0, stream>>>(Wkv, wkvb, 128 * C_ / 4);
  cast_k<<<(C_ * C_ / 4) / 256, 256, 0, stream>>>(Wo, wob, C_ * C_ / 4);

  // q = xn @ Wq^T; fold SCALE * log2(e) = 0.125 * 1.4426950408889634
  gemm_bt<0><<<dim3(C_ / 128, R / 128), 256, 0, stream>>>(xn, wqb, qbuf, nullptr,
                                                          0.18033688011112042f,
                                                          (int)R, C_, C_);
  // kv = x @ Wkv^T (RAW x per reference)
  gemm_bt<0><<<dim3(1, R / 128), 256, 0, stream>>>(xb, wkvb, kvb, nullptr, 1.0f,
                                                   (int)R, 128, C_);
  vtrans_k<<<(int)(R / 64), 256, 0, stream>>>(kvb, vtb);  // overwrites wqb (dead)
  attn_k<<<B_ * H_ * (N_ / 128), 256, 0, stream>>>(qbuf, kvb, vtb, aob);
  // out = (ao @ Wo^T) * ls_scale[col], fp32
  gemm_bt<1><<<dim3(C_ / 128, R / 128), 256, 0, stream>>>(aob, wob, out, ls, 1.0f,
                                                          (int)R, C_, C_);
}

// Round 6
// 204.857 us; speedup vs baseline: 1.6556x; 1.0632x over previous
//
#include <hip/hip_runtime.h>
#include <hip/hip_bf16.h>
#include <stdint.h>

typedef __attribute__((ext_vector_type(8))) short short8;
typedef __attribute__((ext_vector_type(4))) float f32x4;
typedef __attribute__((ext_vector_type(4))) unsigned short us4;

#define B_ 4
#define N_ 2048
#define C_ 1024
#define H_ 16
#define D_ 64
#define PSTR 68  // P-row stride: 64 kv cols + 4 pad

__device__ __forceinline__ unsigned short f2bf(float f) {
  union { float f; unsigned u; } v; v.f = f;
  unsigned u = v.u;
  u += 0x7fffu + ((u >> 16) & 1u);
  return (unsigned short)(u >> 16);
}

// compiler-visible bf16 convert (RNE) — emits hw cvt, unlike manual f2bf
__device__ __forceinline__ unsigned short bfc(float f) {
  union { __hip_bfloat16 h; unsigned short u; } v;
  v.h = __float2bfloat16(f);
  return v.u;
}

__device__ __forceinline__ void glds16(const unsigned short* g, const unsigned short* l) {
  __builtin_amdgcn_global_load_lds(
      (const __attribute__((address_space(1))) void*)(uintptr_t)g,
      (__attribute__((address_space(3))) void*)(uintptr_t)l, 16, 0, 0);
}

__device__ __forceinline__ f32x4 mfma16(short8 a, short8 b, f32x4 c) {
  return __builtin_amdgcn_mfma_f32_16x16x32_bf16(a, b, c, 0, 0, 0);
}

// ---------------- prep: row std (ddof=1) -> xn bf16, x bf16 ----------------
__global__ __launch_bounds__(256) void prep_k(const float* __restrict__ x,
                                              const float* __restrict__ gamma,
                                              unsigned short* __restrict__ xn,
                                              unsigned short* __restrict__ xb) {
  const int row = blockIdx.x, t = threadIdx.x;
  const float4 v = ((const float4*)(x + (size_t)row * C_))[t];
  float s1 = v.x + v.y + v.z + v.w;
  float s2 = v.x * v.x + v.y * v.y + v.z * v.z + v.w * v.w;
#pragma unroll
  for (int off = 32; off > 0; off >>= 1) {
    s1 += __shfl_down(s1, off);
    s2 += __shfl_down(s2, off);
  }
  __shared__ float r1[4], r2[4];
  if ((t & 63) == 0) { r1[t >> 6] = s1; r2[t >> 6] = s2; }
  __syncthreads();
  s1 = r1[0] + r1[1] + r1[2] + r1[3];
  s2 = r2[0] + r2[1] + r2[2] + r2[3];
  const float var = (s2 - s1 * s1 * (1.0f / C_)) * (1.0f / (C_ - 1));
  const float rstd = 1.0f / (sqrtf(var) + 1e-7f);
  const float4 gv = ((const float4*)gamma)[t];
  us4 a, b;
  a.x = f2bf(v.x); a.y = f2bf(v.y); a.z = f2bf(v.z); a.w = f2bf(v.w);
  b.x = f2bf(v.x * rstd * gv.x); b.y = f2bf(v.y * rstd * gv.y);
  b.z = f2bf(v.z * rstd * gv.z); b.w = f2bf(v.w * rstd * gv.w);
  ((us4*)(xb + (size_t)row * C_))[t] = a;
  ((us4*)(xn + (size_t)row * C_))[t] = b;
}

// ---------------- fp32 -> bf16 cast ----------------
__global__ __launch_bounds__(256) void cast_k(const float* __restrict__ s,
                                              unsigned short* __restrict__ d, int n4) {
  const int i = blockIdx.x * 256 + threadIdx.x;
  if (i >= n4) return;
  const float4 v = ((const float4*)s)[i];
  us4 o; o.x = f2bf(v.x); o.y = f2bf(v.y); o.z = f2bf(v.z); o.w = f2bf(v.w);
  ((us4*)d)[i] = o;
}

// ---------------- V transpose: kvb[n][64+d] -> vtb[b][d][n%2048] ------------
__global__ __launch_bounds__(256) void vtrans_k(const unsigned short* __restrict__ kvb,
                                                unsigned short* __restrict__ vtb) {
  __shared__ unsigned short T[64][68];
  const int t = threadIdx.x, nt = blockIdx.x;
  const int r = t >> 2, c4 = t & 3;
  const unsigned short* src = kvb + (size_t)(nt * 64 + r) * 128 + 64 + c4 * 16;
  *(short8*)&T[r][c4 * 16] = *(const short8*)src;
  *(short8*)&T[r][c4 * 16 + 8] = *(const short8*)(src + 8);
  __syncthreads();
  const int d = t >> 2, nq = t & 3;
  const int b = nt >> 5, nn0 = (nt & 31) * 64 + nq * 16;
  unsigned short* dst = vtb + ((size_t)b * 64 + d) * 2048 + nn0;
  short8 o0, o1;
#pragma unroll
  for (int j = 0; j < 8; ++j) {
    o0[j] = (short)T[nq * 16 + j][d];
    o1[j] = (short)T[nq * 16 + 8 + j][d];
  }
  *(short8*)dst = o0;
  *(short8*)(dst + 8) = o1;
}

// ---------------- GEMM: C[M,N] = A[M,K] * Bw[N,K]^T ------------------------
template <int EPI>
__global__ __launch_bounds__(256, 2) void gemm_bt(const unsigned short* __restrict__ A,
                                                  const unsigned short* __restrict__ Bw,
                                                  void* __restrict__ Cout,
                                                  const float* __restrict__ colscale,
                                                  float uscale, int M, int N, int K) {
  __shared__ unsigned short At[128 * 32];
  __shared__ unsigned short Bt[128 * 32];
  const int t = threadIdx.x;
  const int w = t >> 6, l = t & 63;
  const int ql = l & 15, g = l >> 4;
  const int wr = (w >> 1) * 64, wc = (w & 1) * 64;
  const int m0 = blockIdx.y * 128, n0 = blockIdx.x * 128;

  const int pr0 = t >> 2, pb0 = t & 3;
  const int lb0 = pb0 ^ ((pr0 >> 1) & 3);
  const int pr1 = 64 + (t >> 2);
  const int lb1 = pb0 ^ ((pr1 >> 1) & 3);
  const unsigned short* Ab = A + (size_t)m0 * K;
  const unsigned short* Bb = Bw + (size_t)n0 * K;

  f32x4 acc[4][4];
#pragma unroll
  for (int i = 0; i < 4; ++i)
#pragma unroll
    for (int j = 0; j < 4; ++j) acc[i][j] = f32x4{0.f, 0.f, 0.f, 0.f};

  for (int k0 = 0; k0 < K; k0 += 32) {
    glds16(Ab + (size_t)pr0 * K + k0 + lb0 * 8, &At[w * 512]);
    glds16(Ab + (size_t)pr1 * K + k0 + lb1 * 8, &At[2048 + w * 512]);
    glds16(Bb + (size_t)pr0 * K + k0 + lb0 * 8, &Bt[w * 512]);
    glds16(Bb + (size_t)pr1 * K + k0 + lb1 * 8, &Bt[2048 + w * 512]);
    __syncthreads();
    short8 af[4], bfr[4];
#pragma unroll
    for (int i = 0; i < 4; ++i) {
      const int row = wr + i * 16 + ql;
      af[i] = *(const short8*)&At[row * 32 + ((g ^ ((row >> 1) & 3)) * 8)];
    }
#pragma unroll
    for (int i = 0; i < 4; ++i) {
      const int row = wc + i * 16 + ql;
      bfr[i] = *(const short8*)&Bt[row * 32 + ((g ^ ((row >> 1) & 3)) * 8)];
    }
#pragma unroll
    for (int mi = 0; mi < 4; ++mi)
#pragma unroll
      for (int ni = 0; ni < 4; ++ni)
        acc[mi][ni] = mfma16(af[mi], bfr[ni], acc[mi][ni]);
    __syncthreads();
  }

  if (EPI == 0) {
    unsigned short* C = (unsigned short*)Cout;
#pragma unroll
    for (int mi = 0; mi < 4; ++mi)
#pragma unroll
      for (int ni = 0; ni < 4; ++ni) {
        const int col = n0 + wc + ni * 16 + ql;
#pragma unroll
        for (int r = 0; r < 4; ++r) {
          const int row = m0 + wr + mi * 16 + g * 4 + r;
          C[(size_t)row * N + col] = f2bf(acc[mi][ni][r] * uscale);
        }
      }
  } else {
    float* C = (float*)Cout;
#pragma unroll
    for (int mi = 0; mi < 4; ++mi)
#pragma unroll
      for (int ni = 0; ni < 4; ++ni) {
        const int col = n0 + wc + ni * 16 + ql;
        const float cs = colscale[col];
#pragma unroll
        for (int r = 0; r < 4; ++r) {
          const int row = m0 + wr + mi * 16 + g * 4 + r;
          C[(size_t)row * N + col] = acc[mi][ni][r] * cs;
        }
      }
  }
}

// ---------------- flash attention (MQA) -------------------------------------
// block = (b, hd, 128 q); 4 waves x 32 q. KVBLK=64, 32 tiles, double-buffered
// K/V staging (glds16, XOR-swizzled source — rule #21): ONE barrier per tile;
// next tile's loads are issued right after the barrier and are drained by the
// NEXT barrier's vmcnt(0), hiding L2 latency under a full tile of compute.
// P exchange is wave-private (Pl[w]) -> lgkmcnt(0) fence, no barrier.
// Softmax in exp2 domain (log2e folded into Q GEMM), defer-max THR=8.
__global__ __launch_bounds__(256, 3) void attn_k(const unsigned short* __restrict__ qb,
                                                 const unsigned short* __restrict__ kvb,
                                                 const unsigned short* __restrict__ vtb,
                                                 unsigned short* __restrict__ ao) {
  __shared__ unsigned short Kt[2][64 * 64];
  __shared__ unsigned short Vt[2][64 * 64];
  __shared__ unsigned short Pl[4][32 * PSTR];

  const int idx = blockIdx.x;
  const int qc = idx & 15, hd = (idx >> 4) & 15, b = idx >> 8;
  const int t = threadIdx.x, w = t >> 6, l = t & 63;
  const int ql = l & 15, g = l >> 4;
  const int q0 = qc * 128 + w * 32;

  // Q fragments (scale incl. log2e folded into the Q GEMM epilogue)
  const unsigned short* qbase = qb + (size_t)(b * N_ + q0) * C_ + hd * D_;
  short8 Qf[2][2];
#pragma unroll
  for (int qs = 0; qs < 2; ++qs)
#pragma unroll
    for (int h = 0; h < 2; ++h)
      Qf[qs][h] = *(const short8*)(qbase + (size_t)(16 * qs + ql) * C_ + 32 * h + 8 * g);

  const unsigned short* kvrow = kvb + (size_t)(b * N_) * 128;
  const unsigned short* vtrow = vtb + (size_t)b * 64 * 2048;
  const int sr = l >> 3;                 // sub-row within an 8-row stage slab
  const int blk = ((l & 7) ^ sr) << 3;   // pre-swizzled source block (shorts)
  const int row0 = 16 * w + sr;          // rows covered by this wave's 2 issues
  const int row1 = row0 + 8;
  const int sw = ql & 7;

  auto stage = [&](int bi, int kt) {
    glds16(kvrow + (size_t)(kt * 64 + row0) * 128 + blk, &Kt[bi][(2 * w) * 512]);
    glds16(kvrow + (size_t)(kt * 64 + row1) * 128 + blk, &Kt[bi][(2 * w + 1) * 512]);
    glds16(vtrow + (size_t)row0 * 2048 + kt * 64 + blk, &Vt[bi][(2 * w) * 512]);
    glds16(vtrow + (size_t)row1 * 2048 + kt * 64 + blk, &Vt[bi][(2 * w + 1) * 512]);
  };

  f32x4 o[2][4];
#pragma unroll
  for (int qs = 0; qs < 2; ++qs)
#pragma unroll
    for (int dt = 0; dt < 4; ++dt) o[qs][dt] = f32x4{0.f, 0.f, 0.f, 0.f};
  float m[2] = {-1e30f, -1e30f}, lsum[2] = {0.f, 0.f};

  stage(0, 0);
  int cur = 0;

  for (int kt = 0; kt < 32; ++kt) {
    __syncthreads();  // buf[cur] staged (vmcnt drained); prev-tile reads done
    if (kt < 31) stage(cur ^ 1, kt + 1);  // async prefetch, drains next barrier

    short8 Kf[4][2];
#pragma unroll
    for (int c = 0; c < 4; ++c) {
      const int roff = (16 * c + ql) * 64;
      Kf[c][0] = *(const short8*)&Kt[cur][roff + ((g ^ sw) << 3)];
      Kf[c][1] = *(const short8*)&Kt[cur][roff + (((g + 4) ^ sw) << 3)];
    }

#pragma unroll
    for (int qs = 0; qs < 2; ++qs) {
      f32x4 s[4];
#pragma unroll
      for (int c = 0; c < 4; ++c) {
        f32x4 acc = {0.f, 0.f, 0.f, 0.f};
        acc = mfma16(Kf[c][0], Qf[qs][0], acc);
        acc = mfma16(Kf[c][1], Qf[qs][1], acc);
        s[c] = acc;
      }
      float tm = fmaxf(fmaxf(s[0][0], s[0][1]), fmaxf(s[0][2], s[0][3]));
#pragma unroll
      for (int c = 1; c < 4; ++c)
        tm = fmaxf(tm, fmaxf(fmaxf(s[c][0], s[c][1]), fmaxf(s[c][2], s[c][3])));
      tm = fmaxf(tm, __shfl_xor(tm, 16));
      tm = fmaxf(tm, __shfl_xor(tm, 32));
      if (!__all(tm <= m[qs] + 8.0f)) {  // defer-max (T13)
        const float mn = fmaxf(m[qs], tm);
        const float corr = __builtin_amdgcn_exp2f(m[qs] - mn);
        lsum[qs] *= corr;
#pragma unroll
        for (int dt = 0; dt < 4; ++dt) o[qs][dt] *= corr;
        m[qs] = mn;
      }
      float ps = 0.f;
#pragma unroll
      for (int c = 0; c < 4; ++c) {
        const float p0 = __builtin_amdgcn_exp2f(s[c][0] - m[qs]);
        const float p1 = __builtin_amdgcn_exp2f(s[c][1] - m[qs]);
        const float p2 = __builtin_amdgcn_exp2f(s[c][2] - m[qs]);
        const float p3 = __builtin_amdgcn_exp2f(s[c][3] - m[qs]);
        ps += (p0 + p1) + (p2 + p3);
        us4 pq;
        pq.x = bfc(p0); pq.y = bfc(p1); pq.z = bfc(p2); pq.w = bfc(p3);
        *(us4*)&Pl[w][(16 * qs + ql) * PSTR + 16 * c + 4 * g] = pq;
      }
      ps += __shfl_xor(ps, 16);
      ps += __shfl_xor(ps, 32);
      lsum[qs] += ps;
    }

    // Pl[w] is wave-private: wave-local LDS fence instead of a barrier.
    // "memory" clobber orders the ds_writes above / ds_reads below at the
    // IR level (regardless of TBAA); lgkmcnt(0) orders them in hardware.
    asm volatile("s_waitcnt lgkmcnt(0)" ::: "memory");
    __builtin_amdgcn_sched_barrier(0);

    short8 Vf[4][2];
#pragma unroll
    for (int dt = 0; dt < 4; ++dt) {
      const int roff = (16 * dt + ql) * 64;
      Vf[dt][0] = *(const short8*)&Vt[cur][roff + ((g ^ sw) << 3)];
      Vf[dt][1] = *(const short8*)&Vt[cur][roff + (((g + 4) ^ sw) << 3)];
    }
    short8 Pf[2][2];
#pragma unroll
    for (int qs = 0; qs < 2; ++qs)
#pragma unroll
      for (int h = 0; h < 2; ++h)
        Pf[qs][h] = *(const short8*)&Pl[w][(16 * qs + ql) * PSTR + 32 * h + 8 * g];

#pragma unroll
    for (int qs = 0; qs < 2; ++qs)
#pragma unroll
      for (int dt = 0; dt < 4; ++dt) {
        f32x4 acc = o[qs][dt];
        acc = mfma16(Vf[dt][0], Pf[qs][0], acc);
        acc = mfma16(Vf[dt][1], Pf[qs][1], acc);
        o[qs][dt] = acc;  // o^T[d][q]
      }
    cur ^= 1;
  }

#pragma unroll
  for (int qs = 0; qs < 2; ++qs) {
    const float inv = 1.0f / lsum[qs];
    unsigned short* orow = ao + (size_t)(b * N_ + q0 + 16 * qs + ql) * C_ + hd * D_;
#pragma unroll
    for (int dt = 0; dt < 4; ++dt) {
      us4 st;
      st.x = bfc(o[qs][dt][0] * inv);
      st.y = bfc(o[qs][dt][1] * inv);
      st.z = bfc(o[qs][dt][2] * inv);
      st.w = bfc(o[qs][dt][3] * inv);
      *(us4*)(orow + dt * 16 + 4 * g) = st;
    }
  }
}

extern "C" void kernel_launch(void* const* d_in, const int* in_sizes, int n_in,
                              void* d_out, int out_size, void* d_ws, size_t ws_size,
                              hipStream_t stream) {
  const float* x = (const float*)d_in[0];
  const float* gamma = (const float*)d_in[1];
  const float* Wq = (const float*)d_in[2];
  const float* Wkv = (const float*)d_in[3];
  const float* Wo = (const float*)d_in[4];
  const float* ls = (const float*)d_in[5];
  float* out = (float*)d_out;

  unsigned short* ws = (unsigned short*)d_ws;
  const size_t R = (size_t)B_ * N_;  // 8192 rows
  unsigned short* xn = ws;                       // R*C
  unsigned short* xb = xn + R * C_;              // R*C
  unsigned short* qbuf = xb + R * C_;            // R*C
  unsigned short* kvb = qbuf + R * C_;           // R*128
  unsigned short* aob = kvb + R * 128;           // R*C
  unsigned short* wqb = aob + R * C_;            // C*C
  unsigned short* wkvb = wqb + (size_t)C_ * C_;  // 128*C
  unsigned short* wob = wkvb + (size_t)128 * C_; // C*C  (= round-1 footprint)
  // vtb ALIASES wqb: Wq-bf16 is dead after the Q-GEMM; vtrans fully rewrites
  // this region every call before attn reads it (graph-replay deterministic).
  unsigned short* vtb = wqb;                     // 4*64*2048 <= C*C

  prep_k<<<(int)R, 256, 0, stream>>>(x, gamma, xn, xb);
  cast_k<<<(C_ * C_ / 4) / 256, 256, 0, stream>>>(Wq, wqb, C_ * C_ / 4);
  cast_k<<<(128 * C_ / 4) / 256, 256, 0, stream>>>(Wkv, wkvb, 128 * C_ / 4);
  cast_k<<<(C_ * C_ / 4) / 256, 256, 0, stream>>>(Wo, wob, C_ * C_ / 4);

  // q = xn @ Wq^T; fold SCALE * log2(e) = 0.125 * 1.4426950408889634
  gemm_bt<0><<<dim3(C_ / 128, R / 128), 256, 0, stream>>>(xn, wqb, qbuf, nullptr,
                                                          0.18033688011112042f,
                                                          (int)R, C_, C_);
  // kv = x @ Wkv^T (RAW x per reference)
  gemm_bt<0><<<dim3(1, R / 128), 256, 0, stream>>>(xb, wkvb, kvb, nullptr, 1.0f,
                                                   (int)R, 128, C_);
  vtrans_k<<<(int)(R / 64), 256, 0, stream>>>(kvb, vtb);  // overwrites wqb (dead)
  attn_k<<<B_ * H_ * (N_ / 128), 256, 0, stream>>>(qbuf, kvb, vtb, aob);
  // out = (ao @ Wo^T) * ls_scale[col], fp32
  gemm_bt<1><<<dim3(C_ / 128, R / 128), 256, 0, stream>>>(aob, wob, out, ls, 1.0f,
                                                          (int)R, C_, C_);
}